// Round 10
// baseline (498.748 us; speedup 1.0000x reference)
//
#include <hip/hip_runtime.h>

// TorchGrouper R10 — DIAGNOSTIC round: R6 kernel (best, 194.5us) wrapped in a
// runtime reps=3 loop so our dispatch (~585us) outranks the harness's 410us
// fill kernels in the rocprof top-5 and finally reveals OUR FETCH_SIZE /
// WRITE_SIZE. Idempotent: each rep writes identical correct values.
// Decision rule: FETCH >= ~1.8GB -> gathers are HBM-granule-bound, R6 was at
// ~91% of 8TB/s -> declare roofline (restore R6). FETCH <= ~1.0GB -> table is
// L3-resident and ~80us is recoverable elsewhere.

typedef float f32x4 __attribute__((ext_vector_type(4)));

constexpr int G  = 40000;
constexpr int C  = 64;
constexpr int VZ = 40, VY = 400, VX = 400;
constexpr size_t GO = (size_t)G * 64;
constexpr int NBLK = G / 4;           // 10000
constexpr int CHUNK8 = NBLK / 8;      // 1250

__device__ __forceinline__ void store_sysnt_x1(float* p, float v) {
    asm volatile("global_store_dword %0, %1, off sc0 sc1 nt"
                 :: "v"(p), "v"(v) : "memory");
}
__device__ __forceinline__ void store_sysnt_x4(float* p, f32x4 v) {
    asm volatile("global_store_dwordx4 %0, %1, off sc0 sc1 nt"
                 :: "v"(p), "v"(v) : "memory");
}

__global__ __launch_bounds__(256) void grouper_kernel(
    const int*   __restrict__ vox,
    const float* __restrict__ gpos,
    const float* __restrict__ feat,
    float*       __restrict__ out,
    int reps)
{
    __shared__ __align__(16) float lds[4][64 * 32];   // 32 KB/block

    const int blk = (blockIdx.x & 7) * CHUNK8 + (blockIdx.x >> 3);
    const int wid  = threadIdx.x >> 6;
    const int lane = threadIdx.x & 63;
    const int g = blk * 4 + wid;
    const int o = lane;

    const int rtab4[4] = {-3, -2, 1, 2};
    const int rx = rtab4[o & 3];          // added to z
    const int ry = rtab4[(o >> 2) & 3];   // added to y
    const int rz = rtab4[(o >> 4) & 3];   // added to x

    for (int rep = 0; rep < reps; ++rep) {
        const float4 p = ((const float4*)gpos)[g];        // (b,z,y,x)
        const float zf = p.y + (float)rx;
        const float yf = p.z + (float)ry;
        const float xf = p.w + (float)rz;

        const int bi = (int)p.x;                          // trunc-toward-zero
        const int zi = min(max((int)zf, 0), VZ - 1);
        const int yi = min(max((int)yf, 0), VY - 1);
        const int xi = min(max((int)xf, 0), VX - 1);

        const int idx = vox[((bi * VZ + zi) * VY + yi) * VX + xi];

        // ---- gpf [1,3,G,64] + empty mask
        float* gout = out + C * GO;
        const size_t t = (size_t)g * 64 + o;
        store_sysnt_x1(gout + t,          zf - truncf(zf));
        store_sysnt_x1(gout + GO + t,     yf - truncf(yf) + (float)rx);
        store_sysnt_x1(gout + 2 * GO + t, xf - truncf(xf) + (float)ry);
        const int allm1 = __all(idx == -1);
        if (o == 0) store_sysnt_x1(gout + 3 * GO + g, allm1 ? 1.0f : 0.0f);

        // ---- sampled_features via LDS transpose
        float* tile = lds[wid];
        const int d  = lane >> 3;   // phase A: row-within-group (0..7)
        const int c4 = lane & 7;    // phase A: col group (0..7)
        const int q  = lane >> 4;   // phase B: col low bits (0..3)
        const int m  = lane & 15;   // phase B: o-group (0..15)

        #pragma unroll
        for (int chunk = 0; chunk < 2; ++chunk) {
            #pragma unroll
            for (int i = 0; i < 8; ++i) {
                const int r    = i * 8 + d;
                const int ridx = __shfl(idx, r);
                const bool emp = ridx < 0;
                const int  rr  = emp ? 0 : ridx;
                f32x4 v = *(const f32x4*)(feat + (size_t)rr * C + chunk * 32 + c4 * 4);
                if (emp) { v.x = 0.0f; v.y = 0.0f; v.z = 0.0f; v.w = 0.0f; }
                const int cs = c4 ^ ((r >> 2) & 7);       // bank swizzle
                *(f32x4*)(tile + r * 32 + cs * 4) = v;
            }
            asm volatile("s_waitcnt lgkmcnt(0)" ::: "memory");

            #pragma unroll
            for (int i = 0; i < 8; ++i) {
                const int ip = (i ^ (m & 7)) * 4 + q;
                f32x4 sv;
                sv.x = tile[(m * 4 + 0) * 32 + ip];
                sv.y = tile[(m * 4 + 1) * 32 + ip];
                sv.z = tile[(m * 4 + 2) * 32 + ip];
                sv.w = tile[(m * 4 + 3) * 32 + ip];
                const size_t c = (size_t)(chunk * 32 + i * 4 + q);
                store_sysnt_x4(out + c * GO + (size_t)g * 64 + m * 4, sv);
            }
            asm volatile("s_waitcnt lgkmcnt(0)" ::: "memory");
        }
    }
}

extern "C" void kernel_launch(void* const* d_in, const int* in_sizes, int n_in,
                              void* d_out, int out_size, void* d_ws, size_t ws_size,
                              hipStream_t stream) {
    const int*   vox  = (const int*)d_in[0];
    const float* gpos = (const float*)d_in[1];
    const float* feat = (const float*)d_in[2];
    float*       out  = (float*)d_out;

    grouper_kernel<<<NBLK, 256, 0, stream>>>(vox, gpos, feat, out, 3);
}

// Round 11
// 194.365 us; speedup vs baseline: 2.5660x; 2.5660x over previous
//
#include <hip/hip_runtime.h>

// TorchGrouper — FINAL (restore R6 best: 194.5us).
// G=40000, O=64 offsets (4^3 hollow cube, r={-3,-2,1,2}), C=64 channels.
// vox: int32 [2,40,400,400]; gpos: f32 [G,4] (b,z,y,x); feat: f32 [100000,64].
// Out concat: sampled_features [1,64,G,64] | gpf [1,3,G,64] | empty_mask [G]
// Wave = one g, lane = o. Feature path via swizzled LDS transpose; all output
// stores system-scope non-temporal (sc0 sc1 nt; +3% proven in R6).
//
// Roofline ledger (10 rounds): fabric-side motion = 687MB writes + 655MB
// logical gathers + ~80MB voxel = ~1.42GB / 194.5us = 7.3 TB/s, above the
// fill kernel's demonstrated 6.7 TB/s. FETCH=169MB/rep (L3 absorbs reads),
// WRITE=687MB/rep (ideal). All structural levers null or negative except
// cache policy (+3%). This is the fabric/data-motion roofline.

typedef float f32x4 __attribute__((ext_vector_type(4)));

constexpr int G  = 40000;
constexpr int C  = 64;
constexpr int VZ = 40, VY = 400, VX = 400;
constexpr size_t GO = (size_t)G * 64;
constexpr int NBLK = G / 4;           // 10000
constexpr int CHUNK8 = NBLK / 8;      // 1250

__device__ __forceinline__ void store_sysnt_x1(float* p, float v) {
    asm volatile("global_store_dword %0, %1, off sc0 sc1 nt"
                 :: "v"(p), "v"(v) : "memory");
}
__device__ __forceinline__ void store_sysnt_x4(float* p, f32x4 v) {
    asm volatile("global_store_dwordx4 %0, %1, off sc0 sc1 nt"
                 :: "v"(p), "v"(v) : "memory");
}

__global__ __launch_bounds__(256) void grouper_kernel(
    const int*   __restrict__ vox,
    const float* __restrict__ gpos,
    const float* __restrict__ feat,
    float*       __restrict__ out)
{
    __shared__ __align__(16) float lds[4][64 * 32];   // 32 KB/block

    // Bijective XCD swizzle (neutral, harmless).
    const int blk = (blockIdx.x & 7) * CHUNK8 + (blockIdx.x >> 3);

    const int wid  = threadIdx.x >> 6;
    const int lane = threadIdx.x & 63;
    const int g = blk * 4 + wid;
    const int o = lane;

    // offsets r = {-3,-2,1,2}
    const int rtab4[4] = {-3, -2, 1, 2};
    const int rx = rtab4[o & 3];          // added to z
    const int ry = rtab4[(o >> 2) & 3];   // added to y
    const int rz = rtab4[(o >> 4) & 3];   // added to x

    const float4 p = ((const float4*)gpos)[g];        // (b,z,y,x)
    const float zf = p.y + (float)rx;
    const float yf = p.z + (float)ry;
    const float xf = p.w + (float)rz;

    const int bi = (int)p.x;                          // trunc-toward-zero
    const int zi = min(max((int)zf, 0), VZ - 1);
    const int yi = min(max((int)yf, 0), VY - 1);
    const int xi = min(max((int)xf, 0), VX - 1);

    const int idx = vox[((bi * VZ + zi) * VY + yi) * VX + xi];

    // ---- gpf [1,3,G,64]: (z,y,x) frac + quirk (+0, +rx, +ry); empty mask
    float* gout = out + C * GO;
    const size_t t = (size_t)g * 64 + o;
    store_sysnt_x1(gout + t,          zf - truncf(zf));
    store_sysnt_x1(gout + GO + t,     yf - truncf(yf) + (float)rx);
    store_sysnt_x1(gout + 2 * GO + t, xf - truncf(xf) + (float)ry);
    const int allm1 = __all(idx == -1);
    if (o == 0) store_sysnt_x1(gout + 3 * GO + g, allm1 ? 1.0f : 0.0f);

    // ---- sampled_features via LDS transpose
    float* tile = lds[wid];
    const int d  = lane >> 3;   // phase A: row-within-group (0..7)
    const int c4 = lane & 7;    // phase A: col group (0..7)
    const int q  = lane >> 4;   // phase B: col low bits (0..3)
    const int m  = lane & 15;   // phase B: o-group (0..15)

    #pragma unroll
    for (int chunk = 0; chunk < 2; ++chunk) {
        // Phase A: 8 rows per instruction, 16B/lane, swizzled LDS write.
        #pragma unroll
        for (int i = 0; i < 8; ++i) {
            const int r    = i * 8 + d;               // LDS row = offset index o
            const int ridx = __shfl(idx, r);
            const bool emp = ridx < 0;
            const int  rr  = emp ? 0 : ridx;
            f32x4 v = *(const f32x4*)(feat + (size_t)rr * C + chunk * 32 + c4 * 4);
            if (emp) { v.x = 0.0f; v.y = 0.0f; v.z = 0.0f; v.w = 0.0f; }
            const int cs = c4 ^ ((r >> 2) & 7);       // bank swizzle
            *(f32x4*)(tile + r * 32 + cs * 4) = v;
        }
        asm volatile("s_waitcnt lgkmcnt(0)" ::: "memory");

        // Phase B: gather 4 o's per lane from LDS, 1KB dwordx4 nt store.
        #pragma unroll
        for (int i = 0; i < 8; ++i) {
            const int ip = (i ^ (m & 7)) * 4 + q;     // swizzled col for rows 4m..4m+3
            f32x4 sv;
            sv.x = tile[(m * 4 + 0) * 32 + ip];
            sv.y = tile[(m * 4 + 1) * 32 + ip];
            sv.z = tile[(m * 4 + 2) * 32 + ip];
            sv.w = tile[(m * 4 + 3) * 32 + ip];
            const size_t c = (size_t)(chunk * 32 + i * 4 + q);
            store_sysnt_x4(out + c * GO + (size_t)g * 64 + m * 4, sv);
        }
        asm volatile("s_waitcnt lgkmcnt(0)" ::: "memory");
    }
}

extern "C" void kernel_launch(void* const* d_in, const int* in_sizes, int n_in,
                              void* d_out, int out_size, void* d_ws, size_t ws_size,
                              hipStream_t stream) {
    const int*   vox  = (const int*)d_in[0];
    const float* gpos = (const float*)d_in[1];
    const float* feat = (const float*)d_in[2];
    float*       out  = (float*)d_out;

    grouper_kernel<<<NBLK, 256, 0, stream>>>(vox, gpos, feat, out);
}